// Round 4
// baseline (5003.498 us; speedup 1.0000x reference)
//
#include <hip/hip_runtime.h>
#include <hip/hip_bf16.h>

#define BB 4
#define CC 64
#define HH 96
#define WW 384
#define HW (HH*WW)          // 36864
#define CHW (CC*HW)         // 2359296
#define BH (BB*HH)          // 384
#define EPSV 1e-6f
#define QSCALE 0.125f       // C^-0.5, folded into Q_l

typedef __hip_bfloat16 bf16;

__device__ __forceinline__ float b2f(bf16 v){ return __bfloat162float(v); }
__device__ __forceinline__ unsigned short f2bu(float f){
    bf16 h = __float2bfloat16(f);
    return __builtin_bit_cast(unsigned short, h);
}

// ---------------- workspace layout (per-batch A chunk) ----------------
// A_buf: bf16 [HH][WW][WW]  = 28,311,552 bytes
// then f32: rmax, irsum, cmax, icsum, mask_r2l, mask_l2r  (each BH*WW)
// then 4 doubles
#define ACHUNK ((size_t)HH*WW*WW)    // 14,155,776 elems
#define SST ((size_t)BH*WW)          // 147456

// ---------------- K0: zero loss accumulators ----------------
__global__ void k0_zero(double* dsum){
    if (threadIdx.x < 4) dsum[threadIdx.x] = 0.0;
}

// ---------------- K2f: fused LN + proj1 + attention A = Q_l^T Q_r ----------------
// grid (6 wtiles, HH), block 256. One batch b per launch.
__global__ __launch_bounds__(256) void k2f(
    const float* __restrict__ xl, const float* __restrict__ xr,
    const float* __restrict__ nlw, const float* __restrict__ nlb,
    const float* __restrict__ nrw, const float* __restrict__ nrb,
    const float* __restrict__ P1l, const float* __restrict__ b1l,
    const float* __restrict__ P1r, const float* __restrict__ b1r,
    bf16* __restrict__ Abuf, int b)
{
    __shared__ float xls[64*64];                 // [c][w]
    __shared__ float p1ls[64*65], p1rs[64*65];   // [o][c]
    __shared__ float qls[64*64], qrs[64*64];     // [c(=o)][w]
    __shared__ float mus[64], ris[64];
    __shared__ float nlws[64], nlbs[64], nrws[64], nrbs[64], b1ls[64], b1rs[64];

    int t  = threadIdx.x;
    int wt = blockIdx.x, l = blockIdx.y;
    int w0 = wt*64;

    if (t < 64){ nlws[t]=nlw[t]; nlbs[t]=nlb[t]; nrws[t]=nrw[t]; nrbs[t]=nrb[t];
                 b1ls[t]=b1l[t]; b1rs[t]=b1r[t]; }
    for (int k=0;k<16;k++){
        int i=t+256*k; int o=i>>6, c=i&63;
        p1ls[o*65+c]=P1l[i]; p1rs[o*65+c]=P1r[i];
    }
    const float* xlb = xl + (size_t)b*CHW + (size_t)l*WW + w0;
    for (int k=0;k<16;k++){
        int c=(t>>6)+4*k, w=t&63;
        xls[c*64+w] = xlb[(size_t)c*HW + w];
    }
    __syncthreads();
    if (t < 64){
        float s=0.f, ss=0.f;
        for (int c=0;c<64;c++){ float v=xls[c*64+t]; s+=v; ss+=v*v; }
        float mu=s*(1.f/64.f), var=ss*(1.f/64.f)-mu*mu;
        mus[t]=mu; ris[t]=rsqrtf(var+EPSV);
    }
    __syncthreads();

    // Q_l tile: thread (oq = t>>4, wq = t&15), 4x4
    {
        int wq=t&15, oq=t>>4;
        float muj[4], rij[4];
        for (int j=0;j<4;j++){ muj[j]=mus[wq*4+j]; rij[j]=ris[wq*4+j]; }
        float accQ[4][4]={};
        for (int c=0;c<64;c++){
            float nwc=nlws[c], nbc=nlbs[c];
            float xn[4];
            for (int j=0;j<4;j++) xn[j]=(xls[c*64+wq*4+j]-muj[j])*rij[j]*nwc+nbc;
            for (int i=0;i<4;i++){
                float w1=p1ls[(oq*4+i)*65+c];
                for (int j=0;j<4;j++) accQ[i][j]+=w1*xn[j];
            }
        }
        for (int i=0;i<4;i++)
            for (int j=0;j<4;j++)
                qls[(oq*4+i)*64 + wq*4+j] = QSCALE*(accQ[i][j]+b1ls[oq*4+i]);
    }

    bf16* Ab = Abuf + (size_t)l*WW*WW;
    int vg=t&15, wg=t>>4;
    for (int vt=0; vt<6; vt++){
        int v0=vt*64;
        __syncthreads();   // protect xls & qrs reuse
        const float* xrb = xr + (size_t)b*CHW + (size_t)l*WW + v0;
        for (int k=0;k<16;k++){
            int c=(t>>6)+4*k, v=t&63;
            xls[c*64+v] = xrb[(size_t)c*HW + v];
        }
        __syncthreads();
        if (t < 64){
            float s=0.f, ss=0.f;
            for (int c=0;c<64;c++){ float v=xls[c*64+t]; s+=v; ss+=v*v; }
            float mu=s*(1.f/64.f), var=ss*(1.f/64.f)-mu*mu;
            mus[t]=mu; ris[t]=rsqrtf(var+EPSV);
        }
        __syncthreads();
        {
            int vq=t&15, oq=t>>4;
            float muj[4], rij[4];
            for (int j=0;j<4;j++){ muj[j]=mus[vq*4+j]; rij[j]=ris[vq*4+j]; }
            float accQ[4][4]={};
            for (int c=0;c<64;c++){
                float nwc=nrws[c], nbc=nrbs[c];
                float xn[4];
                for (int j=0;j<4;j++) xn[j]=(xls[c*64+vq*4+j]-muj[j])*rij[j]*nwc+nbc;
                for (int i=0;i<4;i++){
                    float w1=p1rs[(oq*4+i)*65+c];
                    for (int j=0;j<4;j++) accQ[i][j]+=w1*xn[j];
                }
            }
            for (int i=0;i<4;i++)
                for (int j=0;j<4;j++)
                    qrs[(oq*4+i)*64 + vq*4+j] = accQ[i][j]+b1rs[oq*4+i];
        }
        __syncthreads();
        float acc[4][4]={};  // [j:w][i:v]
        for (int c=0;c<64;c++){
            float lv[4], rv[4];
            for (int j=0;j<4;j++) lv[j]=qls[c*64+wg*4+j];
            for (int i=0;i<4;i++) rv[i]=qrs[c*64+vg*4+i];
            for (int j=0;j<4;j++)
                for (int i=0;i<4;i++) acc[j][i]+=lv[j]*rv[i];
        }
        for (int j=0;j<4;j++){
            int w=w0+wg*4+j;
            ushort4 pk;
            pk.x=f2bu(acc[j][0]); pk.y=f2bu(acc[j][1]); pk.z=f2bu(acc[j][2]); pk.w=f2bu(acc[j][3]);
            *reinterpret_cast<ushort4*>(Ab + (size_t)w*WW + v0 + vg*4) = pk;
        }
    }
}

// ---------------- K3: softmax stats (row + col) ----------------
// grid (HH, 6 segs), block 384
__global__ __launch_bounds__(384) void k3_stats(
    const bf16* __restrict__ Abuf, float* __restrict__ rmax, float* __restrict__ irsum,
    float* __restrict__ cmax, float* __restrict__ icsum, int b)
{
    __shared__ float pm[6][64], ps[6][64];
    int t=threadIdx.x, l=blockIdx.x, seg=blockIdx.y;
    int bh=b*HH+l;
    const bf16* Ab = Abuf + (size_t)l*WW*WW;
    int lane=t&63, wid=t>>6;
    for (int w=seg*64+wid; w<seg*64+64; w+=6){
        const bf16* row=Ab+(size_t)w*WW;
        float m=-1e30f;
        for (int k=0;k<6;k++) m=fmaxf(m,b2f(row[lane+64*k]));
        for (int o=32;o;o>>=1) m=fmaxf(m,__shfl_xor(m,o,64));
        float s=0.f;
        for (int k=0;k<6;k++) s+=__expf(b2f(row[lane+64*k])-m);
        for (int o=32;o;o>>=1) s+=__shfl_xor(s,o,64);
        if (lane==0){ rmax[bh*WW+w]=m; irsum[bh*WW+w]=1.f/s; }
    }
    {
        int c=t&63, v=seg*64+c;
        float m=-1e30f;
        for (int w=wid*64; w<wid*64+64; w++) m=fmaxf(m,b2f(Ab[(size_t)w*WW+v]));
        float s=0.f;
        for (int w=wid*64; w<wid*64+64; w++) s+=__expf(b2f(Ab[(size_t)w*WW+v])-m);
        pm[wid][c]=m; ps[wid][c]=s;
    }
    __syncthreads();
    if (t<64){
        float M=-1e30f;
        for (int p=0;p<6;p++) M=fmaxf(M,pm[p][t]);
        float S=0.f;
        for (int p=0;p<6;p++) S+=ps[p][t]*__expf(pm[p][t]-M);
        cmax[bh*WW+seg*64+t]=M; icsum[bh*WW+seg*64+t]=1.f/S;
    }
}

// ---------------- K4: validity masks ----------------
// grid (HH, 6), block 384
__global__ __launch_bounds__(384) void k4_masks(
    const bf16* __restrict__ Abuf, const float* __restrict__ rmax, const float* __restrict__ irsum,
    const float* __restrict__ cmax, const float* __restrict__ icsum,
    float* __restrict__ mask_r2l, float* __restrict__ mask_l2r, int b)
{
    __shared__ float pa[6][64];
    int t=threadIdx.x, l=blockIdx.x, seg=blockIdx.y;
    int bh=b*HH+l;
    const bf16* Ab = Abuf + (size_t)l*WW*WW;
    const float* rm=rmax+bh*WW; const float* ris=irsum+bh*WW;
    const float* cm=cmax+bh*WW; const float* cis=icsum+bh*WW;
    int lane=t&63, wid=t>>6;
    {
        int c=t&63, v=seg*64+c;
        float s=0.f;
        for (int w=wid*64; w<wid*64+64; w++)
            s+=__expf(b2f(Ab[(size_t)w*WW+v])-rm[w])*ris[w];
        pa[wid][c]=s;
    }
    __syncthreads();
    if (t<64){
        float S=0.f;
        for (int p=0;p<6;p++) S+=pa[p][t];
        mask_r2l[bh*WW+seg*64+t]=(S>0.1f)?1.f:0.f;
    }
    for (int u=seg*64+wid; u<seg*64+64; u+=6){
        const bf16* row=Ab+(size_t)u*WW;
        float s=0.f;
        for (int k=0;k<6;k++){
            int w=lane+64*k;
            s+=__expf(b2f(row[w])-cm[w])*cis[w];
        }
        for (int o=32;o;o>>=1) s+=__shfl_xor(s,o,64);
        if (lane==0) mask_l2r[bh*WW+u]=(s>0.1f)?1.f:0.f;
    }
}

// ---------------- K5f: out = x + coef * (M @ V)^T  (V recomputed from x) ----------------
// grid (6 wtiles, HH), block 256
__global__ __launch_bounds__(256) void k5f(
    const bf16* __restrict__ Abuf, const float* __restrict__ stat_m, const float* __restrict__ stat_is,
    const float* __restrict__ xsrcV, const float* __restrict__ P2, const float* __restrict__ b2,
    const float* __restrict__ xadd, const float* __restrict__ coef,
    float* __restrict__ outp, int b, int side)
{
    __shared__ float Ms[64*65];   // [w][v]
    __shared__ float Vs[64*65];   // [v][c]
    __shared__ float xls[64*64];  // [c][v]
    __shared__ float p2s[64*65];  // [o][c]
    __shared__ float b2s[64], coefs[64];
    int t=threadIdx.x;
    int wt=blockIdx.x, l=blockIdx.y;
    int w0=wt*64, bh=b*HH+l;
    if (t<64){ b2s[t]=b2[t]; coefs[t]=coef[t]; }
    for (int k=0;k<16;k++){
        int i=t+256*k; p2s[(i>>6)*65+(i&63)]=P2[i];
    }
    const bf16* Ab = Abuf + (size_t)l*WW*WW;
    const float* sm=stat_m+bh*WW; const float* sis=stat_is+bh*WW;
    int cg=t&15, wg=t>>4;
    float acc[4][4]={};   // [j:w][i:c]

    for (int vt=0; vt<6; vt++){
        int v0=vt*64;
        __syncthreads();
        if (side==0){
            for (int k=0;k<16;k++){
                int r=(t>>6)+4*k, cc=t&63;
                float a=b2f(Ab[(size_t)(w0+r)*WW+v0+cc]);
                Ms[r*65+cc]=__expf(a-sm[w0+r])*sis[w0+r];
            }
        } else {
            for (int k=0;k<16;k++){
                int r=(t>>6)+4*k, cc=t&63;  // r=v, cc=w
                float a=b2f(Ab[(size_t)(v0+r)*WW+w0+cc]);
                Ms[cc*65+r]=__expf(a-sm[w0+cc])*sis[w0+cc];
            }
        }
        const float* xvb = xsrcV + (size_t)b*CHW + (size_t)l*WW + v0;
        for (int k=0;k<16;k++){
            int c=(t>>6)+4*k, v=t&63;
            xls[c*64+v]=xvb[(size_t)c*HW+v];
        }
        __syncthreads();
        {   // V tile: thread (ov=t>>4, vv=t&15)
            int vv=t&15, ov=t>>4;
            float accV[4][4]={};   // [i:o][j:v]
            for (int c=0;c<64;c++){
                float xvr[4];
                for (int j=0;j<4;j++) xvr[j]=xls[c*64+vv*4+j];
                for (int i=0;i<4;i++){
                    float w2=p2s[(ov*4+i)*65+c];
                    for (int j=0;j<4;j++) accV[i][j]+=w2*xvr[j];
                }
            }
            for (int i=0;i<4;i++)
                for (int j=0;j<4;j++)
                    Vs[(vv*4+j)*65 + ov*4+i]=accV[i][j]+b2s[ov*4+i];
        }
        __syncthreads();
        for (int v=0;v<64;v++){
            float mv[4], vv2[4];
            for (int j=0;j<4;j++) mv[j]=Ms[(wg*4+j)*65+v];
            for (int i=0;i<4;i++) vv2[i]=Vs[v*65+cg*4+i];
            for (int j=0;j<4;j++)
                for (int i=0;i<4;i++) acc[j][i]+=mv[j]*vv2[i];
        }
    }
    const float* xb = xadd + (size_t)b*CHW + (size_t)l*WW + w0;
    float*      ob = outp + (size_t)b*CHW + (size_t)l*WW + w0;
    for (int i=0;i<4;i++){
        int c=cg*4+i;
        for (int j=0;j<4;j++){
            int w=wg*4+j;
            float xv=xb[(size_t)c*HW+w];
            ob[(size_t)c*HW+w]=xv+coefs[c]*acc[j][i];
        }
    }
}

// ---------------- K6: cycle loss GEMMs ----------------
// grid (6 wtiles, HH, 2 which), block 256
__global__ __launch_bounds__(256) void k6_cycle(
    const bf16* __restrict__ Abuf, const float* __restrict__ rmax, const float* __restrict__ irsum,
    const float* __restrict__ cmax, const float* __restrict__ icsum,
    const float* __restrict__ mask_r2l, const float* __restrict__ mask_l2r,
    double* __restrict__ dsum, int b)
{
    __shared__ float As[64*65];
    __shared__ float Bs[64*65];
    int t=threadIdx.x;
    int wt=blockIdx.x, l=blockIdx.y, which=blockIdx.z;
    int w0=wt*64, bh=b*HH+l;
    const bf16* Ab = Abuf + (size_t)l*WW*WW;
    const float* rm=rmax+bh*WW; const float* ris=irsum+bh*WW;
    const float* cm=cmax+bh*WW; const float* cis=icsum+bh*WW;
    const float* msk = which ? (mask_r2l+bh*WW) : (mask_l2r+bh*WW);
    int ug=t&15, wg=t>>4;
    float local=0.f;

    for (int ut=0; ut<6; ut++){
        int u0=ut*64;
        float acc[4][4]={};
        for (int kt=0; kt<6; kt++){
            int v0=kt*64;
            __syncthreads();
            if (which==0){
                for (int k=0;k<16;k++){
                    int r=(t>>6)+4*k, cc=t&63;
                    float a=b2f(Ab[(size_t)(w0+r)*WW+v0+cc]);
                    As[r*65+cc]=__expf(a-rm[w0+r])*ris[w0+r];
                }
                for (int k=0;k<16;k++){
                    int r=(t>>6)+4*k, cc=t&63;
                    float a=b2f(Ab[(size_t)(u0+r)*WW+v0+cc]);
                    Bs[r*65+cc]=__expf(a-cm[v0+cc])*cis[v0+cc];
                }
            } else {
                for (int k=0;k<16;k++){
                    int r=(t>>6)+4*k, cc=t&63;  // r=v, cc=w
                    float a=b2f(Ab[(size_t)(v0+r)*WW+w0+cc]);
                    As[cc*65+r]=__expf(a-cm[w0+cc])*cis[w0+cc];
                }
                for (int k=0;k<16;k++){
                    int r=(t>>6)+4*k, cc=t&63;  // r=v, cc=u
                    float a=b2f(Ab[(size_t)(v0+r)*WW+u0+cc]);
                    Bs[cc*65+r]=__expf(a-rm[v0+r])*ris[v0+r];
                }
            }
            __syncthreads();
            for (int v=0;v<64;v++){
                float av[4], bv[4];
                for (int j=0;j<4;j++) av[j]=As[(wg*4+j)*65+v];
                for (int i=0;i<4;i++) bv[i]=Bs[(ug*4+i)*65+v];
                for (int j=0;j<4;j++)
                    for (int i=0;i<4;i++) acc[j][i]+=av[j]*bv[i];
            }
        }
        for (int i=0;i<4;i++){
            int u=u0+ug*4+i;
            float m=msk[u];
            for (int j=0;j<4;j++){
                int w=w0+wg*4+j;
                float d=acc[j][i]-((u==w)?1.f:0.f);
                local+=m*fabsf(d);
            }
        }
    }
    for (int o=32;o;o>>=1) local+=__shfl_xor(local,o,64);
    if ((t&63)==0) atomicAdd(&dsum[0],(double)local);
}

// ---------------- K7: photometric loss + LR passthrough ----------------
// grid (HH, 6), block 384
__global__ __launch_bounds__(384) void k7_photo(
    const bf16* __restrict__ Abuf, const float* __restrict__ rmax, const float* __restrict__ irsum,
    const float* __restrict__ cmax, const float* __restrict__ icsum,
    const float* __restrict__ mask_r2l, const float* __restrict__ mask_l2r,
    const float* __restrict__ LRl, const float* __restrict__ LRr,
    float* __restrict__ out2, float* __restrict__ out3, double* __restrict__ dsum, int b)
{
    __shared__ float lrl[3*WW], lrr[3*WW];
    __shared__ float pa0[6][64], pa1[6][64], pa2[6][64];
    int t=threadIdx.x, l=blockIdx.x, seg=blockIdx.y;
    int bh=b*HH+l;
    for (int c=0;c<3;c++){
        size_t idx=((size_t)(b*3+c)*HH+l)*WW+t;
        float vl=LRl[idx], vr=LRr[idx];
        lrl[c*WW+t]=vl; lrr[c*WW+t]=vr;
        if (seg==0){ out2[idx]=vl; out3[idx]=vr; }
    }
    __syncthreads();
    const bf16* Ab = Abuf + (size_t)l*WW*WW;
    const float* rm=rmax+bh*WW; const float* ris=irsum+bh*WW;
    const float* cm=cmax+bh*WW; const float* cis=icsum+bh*WW;
    int lane=t&63, wid=t>>6;
    float local=0.f;
    for (int w=seg*64+wid; w<seg*64+64; w+=6){
        const bf16* row=Ab+(size_t)w*WW;
        float m0=rm[w], s0=ris[w];
        float a0=0.f,a1=0.f,a2=0.f;
        for (int k=0;k<6;k++){
            int v=lane+64*k;
            float mm=__expf(b2f(row[v])-m0)*s0;
            a0+=mm*lrr[0*WW+v]; a1+=mm*lrr[1*WW+v]; a2+=mm*lrr[2*WW+v];
        }
        for (int o=32;o;o>>=1){
            a0+=__shfl_xor(a0,o,64); a1+=__shfl_xor(a1,o,64); a2+=__shfl_xor(a2,o,64);
        }
        if (lane==0){
            float mk=mask_l2r[bh*WW+w];
            local+=mk*(fabsf(lrl[0*WW+w]-a0)+fabsf(lrl[1*WW+w]-a1)+fabsf(lrl[2*WW+w]-a2));
        }
    }
    {
        int c=t&63, w=seg*64+c;
        float m0=cm[w], s0=cis[w];
        float a0=0.f,a1=0.f,a2=0.f;
        for (int v=wid*64; v<wid*64+64; v++){
            float mm=__expf(b2f(Ab[(size_t)v*WW+w])-m0)*s0;
            a0+=mm*lrl[0*WW+v]; a1+=mm*lrl[1*WW+v]; a2+=mm*lrl[2*WW+v];
        }
        pa0[wid][c]=a0; pa1[wid][c]=a1; pa2[wid][c]=a2;
    }
    __syncthreads();
    if (t<64){
        int w=seg*64+t;
        float A0=0.f,A1=0.f,A2=0.f;
        for (int p=0;p<6;p++){ A0+=pa0[p][t]; A1+=pa1[p][t]; A2+=pa2[p][t]; }
        float mk=mask_r2l[bh*WW+w];
        local+=mk*(fabsf(lrr[0*WW+w]-A0)+fabsf(lrr[1*WW+w]-A1)+fabsf(lrr[2*WW+w]-A2));
    }
    for (int o=32;o;o>>=1) local+=__shfl_xor(local,o,64);
    if ((t&63)==0) atomicAdd(&dsum[1],(double)local);
}

// ---------------- K8: smoothness losses ----------------
// grid (HH, 6), block 384
__global__ __launch_bounds__(384) void k8_smooth(
    const bf16* __restrict__ Abuf, const float* __restrict__ rmax, const float* __restrict__ irsum,
    const float* __restrict__ cmax, const float* __restrict__ icsum,
    double* __restrict__ dsum, int b)
{
    int t=threadIdx.x, l=blockIdx.x, seg=blockIdx.y;
    int bh=b*HH+l;
    const bf16* Ab = Abuf + (size_t)l*WW*WW;
    const float* rm=rmax+bh*WW; const float* ris=irsum+bh*WW;
    const float* cm=cmax+bh*WW; const float* cis=icsum+bh*WW;
    int c=t&63, wid=t>>6;
    float lw=0.f, lh=0.f;
    {
        int v=seg*64+c;
        if (v<WW-1){
            int wend=min(WW-1,(wid+1)*64);
            for (int w=wid*64; w<wend; w++){
                float m1=__expf(b2f(Ab[(size_t)w*WW+v])-rm[w])*ris[w];
                float m2=__expf(b2f(Ab[(size_t)(w+1)*WW+v+1])-rm[w+1])*ris[w+1];
                lw+=fabsf(m1-m2);
            }
        }
    }
    {
        int w=seg*64+c;
        if (w<WW-1){
            int vend=min(WW-1,(wid+1)*64);
            for (int v=wid*64; v<vend; v++){
                float m1=__expf(b2f(Ab[(size_t)v*WW+w])-cm[w])*cis[w];
                float m2=__expf(b2f(Ab[(size_t)(v+1)*WW+w+1])-cm[w+1])*cis[w+1];
                lw+=fabsf(m1-m2);
            }
        }
    }
    if (l < HH-1){
        const bf16* Ab2=Ab+(size_t)WW*WW;
        const float* rm2=rm+WW; const float* ris2=ris+WW;
        const float* cm2=cm+WW; const float* cis2=cis+WW;
        {
            int v=seg*64+c;
            for (int w=wid*64; w<wid*64+64; w++){
                float m1=__expf(b2f(Ab [(size_t)w*WW+v])-rm [w])*ris [w];
                float m2=__expf(b2f(Ab2[(size_t)w*WW+v])-rm2[w])*ris2[w];
                lh+=fabsf(m1-m2);
            }
        }
        {
            int w=seg*64+c;
            float c1=cm[w], i1=cis[w], c2=cm2[w], i2=cis2[w];
            for (int v=wid*64; v<wid*64+64; v++){
                float m1=__expf(b2f(Ab [(size_t)v*WW+w])-c1)*i1;
                float m2=__expf(b2f(Ab2[(size_t)v*WW+w])-c2)*i2;
                lh+=fabsf(m1-m2);
            }
        }
    }
    for (int o=32;o;o>>=1){ lw+=__shfl_xor(lw,o,64); lh+=__shfl_xor(lh,o,64); }
    if ((t&63)==0){
        atomicAdd(&dsum[3],(double)lw);
        atomicAdd(&dsum[2],(double)lh);
    }
}

// ---------------- K9: final loss ----------------
__global__ void k9_final(const double* __restrict__ dsum, const float* __restrict__ lossin,
                         float* __restrict__ out4)
{
    if (threadIdx.x==0){
        double cyc  = dsum[0]/(double)((size_t)BB*HH*WW*WW);
        double photo= dsum[1]/(double)((size_t)BB*3*HH*WW);
        double lhv  = dsum[2]/(double)((size_t)BB*(HH-1)*WW*WW);
        double lwv  = dsum[3]/(double)((size_t)BB*HH*(WW-1)*(WW-1));
        double res  = (double)lossin[0] + 0.0025*(photo + 0.1*(lwv+lhv) + cyc);
        out4[0]=(float)res;
    }
}

extern "C" void kernel_launch(void* const* d_in, const int* in_sizes, int n_in,
                              void* d_out, int out_size, void* d_ws, size_t ws_size,
                              hipStream_t stream)
{
    (void)in_sizes; (void)n_in; (void)out_size; (void)ws_size;
    const float* x_l  = (const float*)d_in[0];
    const float* x_r  = (const float*)d_in[1];
    const float* LRl  = (const float*)d_in[2];
    const float* LRr  = (const float*)d_in[3];
    const float* lossi= (const float*)d_in[4];
    const float* nlw  = (const float*)d_in[5];
    const float* nlb  = (const float*)d_in[6];
    const float* nrw  = (const float*)d_in[7];
    const float* nrb  = (const float*)d_in[8];
    const float* lp1w = (const float*)d_in[9];
    const float* lp1b = (const float*)d_in[10];
    const float* rp1w = (const float*)d_in[11];
    const float* rp1b = (const float*)d_in[12];
    const float* lp2w = (const float*)d_in[13];
    const float* lp2b = (const float*)d_in[14];
    const float* rp2w = (const float*)d_in[15];
    const float* rp2b = (const float*)d_in[16];
    const float* beta = (const float*)d_in[17];
    const float* gamma= (const float*)d_in[18];

    bf16* Abuf = (bf16*)d_ws;
    float* wsf = (float*)((char*)d_ws + ACHUNK*2);   // 28,311,552 bytes
    float* rmax=wsf, *irsum=wsf+SST, *cmax=wsf+2*SST, *icsum=wsf+3*SST;
    float* mask_r2l=wsf+4*SST, *mask_l2r=wsf+5*SST;
    double* dsum=(double*)(wsf+6*SST);

    float* out  = (float*)d_out;
    float* out0 = out;
    float* out1 = out + (size_t)BB*CHW;
    float* out2 = out + 2*(size_t)BB*CHW;
    float* out3 = out2 + (size_t)BB*3*HW;
    float* out4 = out3 + (size_t)BB*3*HW;

    k0_zero<<<1,64,0,stream>>>(dsum);
    for (int b=0;b<BB;b++){
        k2f<<<dim3(6,HH),256,0,stream>>>(x_l,x_r,nlw,nlb,nrw,nrb,lp1w,lp1b,rp1w,rp1b,Abuf,b);
        k3_stats<<<dim3(HH,6),384,0,stream>>>(Abuf,rmax,irsum,cmax,icsum,b);
        k4_masks<<<dim3(HH,6),384,0,stream>>>(Abuf,rmax,irsum,cmax,icsum,mask_r2l,mask_l2r,b);
        k5f<<<dim3(6,HH),256,0,stream>>>(Abuf,rmax,irsum,x_r,rp2w,rp2b,x_l,beta, out0,b,0);
        k5f<<<dim3(6,HH),256,0,stream>>>(Abuf,cmax,icsum,x_l,lp2w,lp2b,x_r,gamma,out1,b,1);
        k6_cycle<<<dim3(6,HH,2),256,0,stream>>>(Abuf,rmax,irsum,cmax,icsum,mask_r2l,mask_l2r,dsum,b);
        k7_photo<<<dim3(HH,6),384,0,stream>>>(Abuf,rmax,irsum,cmax,icsum,mask_r2l,mask_l2r,LRl,LRr,out2,out3,dsum,b);
        k8_smooth<<<dim3(HH,6),384,0,stream>>>(Abuf,rmax,irsum,cmax,icsum,dsum,b);
    }
    k9_final<<<1,64,0,stream>>>(dsum,lossi,out4);
}

// Round 5
// 2936.203 us; speedup vs baseline: 1.7041x; 1.7041x over previous
//
#include <hip/hip_runtime.h>
#include <hip/hip_bf16.h>

#define BB 4
#define CC 64
#define HH 96
#define WW 384
#define HW (HH*WW)          // 36864
#define CHW (CC*HW)         // 2359296
#define BH (BB*HH)          // 384
#define EPSV 1e-6f
#define QSCALE 0.125f       // C^-0.5, folded into Q_l

typedef __hip_bfloat16 bf16;
typedef short s8vec __attribute__((ext_vector_type(8)));   // 8 bf16 = one MFMA frag
typedef float f4vec __attribute__((ext_vector_type(4)));   // MFMA accum

__device__ __forceinline__ float b2f(bf16 v){ return __bfloat162float(v); }
__device__ __forceinline__ bf16 f2b(float v){ return __float2bfloat16(v); }
__device__ __forceinline__ unsigned short f2bu(float f){
    bf16 h = __float2bfloat16(f);
    return __builtin_bit_cast(unsigned short, h);
}

// ---------------- workspace layout (per-batch chunk) ----------------
// buf0: A [HH][WW][WW] bf16  -> overwritten in-place by P = M_r2l
// buf1: LT = M_l2r^T  bf16   (LT[u][v] = M_l2r[v][u])
// buf2: PT = P^T      bf16
// then f32 stats: rmax, irsum, cmax, icsum, mask_r2l, mask_l2r (each BH*WW)
// then 4 doubles
#define ACHUNK ((size_t)HH*WW*WW)    // 14,155,776 elems
#define SST ((size_t)BH*WW)          // 147456

// ---------------- K0: zero loss accumulators ----------------
__global__ void k0_zero(double* dsum){
    if (threadIdx.x < 4) dsum[threadIdx.x] = 0.0;
}

// ---------------- K2f: fused LN + proj1 + attention A = Q_l^T Q_r ----------------
// grid (6 wtiles, HH), block 256. One batch b per launch.  (unchanged from passing round)
__global__ __launch_bounds__(256) void k2f(
    const float* __restrict__ xl, const float* __restrict__ xr,
    const float* __restrict__ nlw, const float* __restrict__ nlb,
    const float* __restrict__ nrw, const float* __restrict__ nrb,
    const float* __restrict__ P1l, const float* __restrict__ b1l,
    const float* __restrict__ P1r, const float* __restrict__ b1r,
    bf16* __restrict__ Abuf, int b)
{
    __shared__ float xls[64*64];                 // [c][w]
    __shared__ float p1ls[64*65], p1rs[64*65];   // [o][c]
    __shared__ float qls[64*64], qrs[64*64];     // [c(=o)][w]
    __shared__ float mus[64], ris[64];
    __shared__ float nlws[64], nlbs[64], nrws[64], nrbs[64], b1ls[64], b1rs[64];

    int t  = threadIdx.x;
    int wt = blockIdx.x, l = blockIdx.y;
    int w0 = wt*64;

    if (t < 64){ nlws[t]=nlw[t]; nlbs[t]=nlb[t]; nrws[t]=nrw[t]; nrbs[t]=nrb[t];
                 b1ls[t]=b1l[t]; b1rs[t]=b1r[t]; }
    for (int k=0;k<16;k++){
        int i=t+256*k; int o=i>>6, c=i&63;
        p1ls[o*65+c]=P1l[i]; p1rs[o*65+c]=P1r[i];
    }
    const float* xlb = xl + (size_t)b*CHW + (size_t)l*WW + w0;
    for (int k=0;k<16;k++){
        int c=(t>>6)+4*k, w=t&63;
        xls[c*64+w] = xlb[(size_t)c*HW + w];
    }
    __syncthreads();
    if (t < 64){
        float s=0.f, ss=0.f;
        for (int c=0;c<64;c++){ float v=xls[c*64+t]; s+=v; ss+=v*v; }
        float mu=s*(1.f/64.f), var=ss*(1.f/64.f)-mu*mu;
        mus[t]=mu; ris[t]=rsqrtf(var+EPSV);
    }
    __syncthreads();

    {
        int wq=t&15, oq=t>>4;
        float muj[4], rij[4];
        for (int j=0;j<4;j++){ muj[j]=mus[wq*4+j]; rij[j]=ris[wq*4+j]; }
        float accQ[4][4]={};
        for (int c=0;c<64;c++){
            float nwc=nlws[c], nbc=nlbs[c];
            float xn[4];
            for (int j=0;j<4;j++) xn[j]=(xls[c*64+wq*4+j]-muj[j])*rij[j]*nwc+nbc;
            for (int i=0;i<4;i++){
                float w1=p1ls[(oq*4+i)*65+c];
                for (int j=0;j<4;j++) accQ[i][j]+=w1*xn[j];
            }
        }
        for (int i=0;i<4;i++)
            for (int j=0;j<4;j++)
                qls[(oq*4+i)*64 + wq*4+j] = QSCALE*(accQ[i][j]+b1ls[oq*4+i]);
    }

    bf16* Ab = Abuf + (size_t)l*WW*WW;
    int vg=t&15, wg=t>>4;
    for (int vt=0; vt<6; vt++){
        int v0=vt*64;
        __syncthreads();
        const float* xrb = xr + (size_t)b*CHW + (size_t)l*WW + v0;
        for (int k=0;k<16;k++){
            int c=(t>>6)+4*k, v=t&63;
            xls[c*64+v] = xrb[(size_t)c*HW + v];
        }
        __syncthreads();
        if (t < 64){
            float s=0.f, ss=0.f;
            for (int c=0;c<64;c++){ float v=xls[c*64+t]; s+=v; ss+=v*v; }
            float mu=s*(1.f/64.f), var=ss*(1.f/64.f)-mu*mu;
            mus[t]=mu; ris[t]=rsqrtf(var+EPSV);
        }
        __syncthreads();
        {
            int vq=t&15, oq=t>>4;
            float muj[4], rij[4];
            for (int j=0;j<4;j++){ muj[j]=mus[vq*4+j]; rij[j]=ris[vq*4+j]; }
            float accQ[4][4]={};
            for (int c=0;c<64;c++){
                float nwc=nrws[c], nbc=nrbs[c];
                float xn[4];
                for (int j=0;j<4;j++) xn[j]=(xls[c*64+vq*4+j]-muj[j])*rij[j]*nwc+nbc;
                for (int i=0;i<4;i++){
                    float w1=p1rs[(oq*4+i)*65+c];
                    for (int j=0;j<4;j++) accQ[i][j]+=w1*xn[j];
                }
            }
            for (int i=0;i<4;i++)
                for (int j=0;j<4;j++)
                    qrs[(oq*4+i)*64 + vq*4+j] = accQ[i][j]+b1rs[oq*4+i];
        }
        __syncthreads();
        float acc[4][4]={};
        for (int c=0;c<64;c++){
            float lv[4], rv[4];
            for (int j=0;j<4;j++) lv[j]=qls[c*64+wg*4+j];
            for (int i=0;i<4;i++) rv[i]=qrs[c*64+vg*4+i];
            for (int j=0;j<4;j++)
                for (int i=0;i<4;i++) acc[j][i]+=lv[j]*rv[i];
        }
        for (int j=0;j<4;j++){
            int w=w0+wg*4+j;
            ushort4 pk;
            pk.x=f2bu(acc[j][0]); pk.y=f2bu(acc[j][1]); pk.z=f2bu(acc[j][2]); pk.w=f2bu(acc[j][3]);
            *reinterpret_cast<ushort4*>(Ab + (size_t)w*WW + v0 + vg*4) = pk;
        }
    }
}

// ---------------- K3: softmax stats (row + col) -- unchanged ----------------
__global__ __launch_bounds__(384) void k3_stats(
    const bf16* __restrict__ Abuf, float* __restrict__ rmax, float* __restrict__ irsum,
    float* __restrict__ cmax, float* __restrict__ icsum, int b)
{
    __shared__ float pm[6][64], ps[6][64];
    int t=threadIdx.x, l=blockIdx.x, seg=blockIdx.y;
    int bh=b*HH+l;
    const bf16* Ab = Abuf + (size_t)l*WW*WW;
    int lane=t&63, wid=t>>6;
    for (int w=seg*64+wid; w<seg*64+64; w+=6){
        const bf16* row=Ab+(size_t)w*WW;
        float m=-1e30f;
        for (int k=0;k<6;k++) m=fmaxf(m,b2f(row[lane+64*k]));
        for (int o=32;o;o>>=1) m=fmaxf(m,__shfl_xor(m,o,64));
        float s=0.f;
        for (int k=0;k<6;k++) s+=__expf(b2f(row[lane+64*k])-m);
        for (int o=32;o;o>>=1) s+=__shfl_xor(s,o,64);
        if (lane==0){ rmax[bh*WW+w]=m; irsum[bh*WW+w]=1.f/s; }
    }
    {
        int c=t&63, v=seg*64+c;
        float m=-1e30f;
        for (int w=wid*64; w<wid*64+64; w++) m=fmaxf(m,b2f(Ab[(size_t)w*WW+v]));
        float s=0.f;
        for (int w=wid*64; w<wid*64+64; w++) s+=__expf(b2f(Ab[(size_t)w*WW+v])-m);
        pm[wid][c]=m; ps[wid][c]=s;
    }
    __syncthreads();
    if (t<64){
        float M=-1e30f;
        for (int p=0;p<6;p++) M=fmaxf(M,pm[p][t]);
        float S=0.f;
        for (int p=0;p<6;p++) S+=ps[p][t]*__expf(pm[p][t]-M);
        cmax[bh*WW+seg*64+t]=M; icsum[bh*WW+seg*64+t]=1.f/S;
    }
}

// ---------------- K_mats: A -> P (in-place) + LT ----------------
// grid (HH, 6), block 256
__global__ __launch_bounds__(256) void k_mats(
    bf16* __restrict__ AP, bf16* __restrict__ LT,
    const float* __restrict__ rmax, const float* __restrict__ irsum,
    const float* __restrict__ cmax, const float* __restrict__ icsum, int b)
{
    int t=threadIdx.x, l=blockIdx.x, seg=blockIdx.y;
    int bh=b*HH+l;
    bf16* Ab  = AP + (size_t)l*WW*WW;
    bf16* LTb = LT + (size_t)l*WW*WW;
    const float* rm=rmax+(size_t)bh*WW; const float* ris=irsum+(size_t)bh*WW;
    const float* cm=cmax+(size_t)bh*WW; const float* cis=icsum+(size_t)bh*WW;
    int lane6=t&63;
    float cmv[6], civ[6];
    for (int s=0;s<6;s++){ cmv[s]=cm[s*64+lane6]; civ[s]=cis[s*64+lane6]; }
    for (int k=0;k<16;k++){
        int w = seg*64 + (t>>6) + 4*k;
        float rmw = rm[w], risw = ris[w];
        for (int s=0;s<6;s++){
            int v = s*64 + lane6;
            size_t idx = (size_t)w*WW + v;
            float a = b2f(Ab[idx]);
            Ab[idx]  = f2b(__expf(a - rmw)*risw);       // P[w][v] = M_r2l[w][v]
            LTb[idx] = f2b(__expf(a - cmv[s])*civ[s]);  // LT[w][v] = M_l2r[v][w]
        }
    }
}

// ---------------- K_trans: PT = P^T (64x64 LDS tile transpose) ----------------
// grid (6, 6, HH), block 256
__global__ __launch_bounds__(256) void k_trans(
    const bf16* __restrict__ Pm, bf16* __restrict__ PTm)
{
    __shared__ float tile[64][65];
    int t=threadIdx.x;
    int ti=blockIdx.x, tj=blockIdx.y, l=blockIdx.z;
    const bf16* Pb = Pm + (size_t)l*WW*WW;
    bf16* PTb = PTm + (size_t)l*WW*WW;
    for (int k=0;k<16;k++){
        int r=(t>>6)+4*k, c=t&63;
        tile[r][c] = b2f(Pb[(size_t)(ti*64+r)*WW + tj*64+c]);
    }
    __syncthreads();
    for (int k=0;k<16;k++){
        int r=(t>>6)+4*k, c=t&63;
        PTb[(size_t)(tj*64+r)*WW + ti*64+c] = f2b(tile[c][r]);
    }
}

// ---------------- K4: validity masks from P / LT ----------------
// grid (HH, 6), block 384
__global__ __launch_bounds__(384) void k4_masks(
    const bf16* __restrict__ Pm, const bf16* __restrict__ LTm,
    float* __restrict__ mask_r2l, float* __restrict__ mask_l2r, int b)
{
    __shared__ float pa[6][64];
    int t=threadIdx.x, l=blockIdx.x, seg=blockIdx.y;
    int bh=b*HH+l;
    const bf16* Pb  = Pm  + (size_t)l*WW*WW;
    const bf16* LTb = LTm + (size_t)l*WW*WW;
    int lane=t&63, wid=t>>6;
    {
        int c=t&63, v=seg*64+c;
        float s=0.f;
        for (int w=wid*64; w<wid*64+64; w++) s+=b2f(Pb[(size_t)w*WW+v]);
        pa[wid][c]=s;
    }
    __syncthreads();
    if (t<64){
        float S=0.f;
        for (int p=0;p<6;p++) S+=pa[p][t];
        mask_r2l[bh*WW+seg*64+t]=(S>0.1f)?1.f:0.f;
    }
    for (int u=seg*64+wid; u<seg*64+64; u+=6){
        const bf16* row=LTb+(size_t)u*WW;
        float s=0.f;
        for (int k=0;k<6;k++) s+=b2f(row[lane+64*k]);
        for (int o=32;o;o>>=1) s+=__shfl_xor(s,o,64);
        if (lane==0) mask_l2r[bh*WW+u]=(s>0.1f)?1.f:0.f;
    }
}

// ---------------- K5f: out = x + coef * (M @ V)^T  (V recomputed, M from P/LT) ----------------
// grid (6 wtiles, HH), block 256
__global__ __launch_bounds__(256) void k5f(
    const bf16* __restrict__ Msrc,
    const float* __restrict__ xsrcV, const float* __restrict__ P2, const float* __restrict__ b2,
    const float* __restrict__ xadd, const float* __restrict__ coef,
    float* __restrict__ outp, int b, int side)
{
    __shared__ float Ms[64*65];   // [w][v]
    __shared__ float Vs[64*65];   // [v][c]
    __shared__ float xls[64*64];  // [c][v]
    __shared__ float p2s[64*65];  // [o][c]
    __shared__ float b2s[64], coefs[64];
    int t=threadIdx.x;
    int wt=blockIdx.x, l=blockIdx.y;
    int w0=wt*64;
    if (t<64){ b2s[t]=b2[t]; coefs[t]=coef[t]; }
    for (int k=0;k<16;k++){
        int i=t+256*k; p2s[(i>>6)*65+(i&63)]=P2[i];
    }
    const bf16* Mb = Msrc + (size_t)l*WW*WW;
    int cg=t&15, wg=t>>4;
    float acc[4][4]={};

    for (int vt=0; vt<6; vt++){
        int v0=vt*64;
        __syncthreads();
        if (side==0){
            // Ms[w][v] = P[w0+w][v0+v]
            for (int k=0;k<16;k++){
                int r=(t>>6)+4*k, cc=t&63;
                Ms[r*65+cc]=b2f(Mb[(size_t)(w0+r)*WW+v0+cc]);
            }
        } else {
            // Ms[w][v] = M_l2r[w0+w][v0+v] = LT[v0+v][w0+w]
            for (int k=0;k<16;k++){
                int r=(t>>6)+4*k, cc=t&63;  // r=v, cc=w
                Ms[cc*65+r]=b2f(Mb[(size_t)(v0+r)*WW+w0+cc]);
            }
        }
        const float* xvb = xsrcV + (size_t)b*CHW + (size_t)l*WW + v0;
        for (int k=0;k<16;k++){
            int c=(t>>6)+4*k, v=t&63;
            xls[c*64+v]=xvb[(size_t)c*HW+v];
        }
        __syncthreads();
        {
            int vv=t&15, ov=t>>4;
            float accV[4][4]={};
            for (int c=0;c<64;c++){
                float xvr[4];
                for (int j=0;j<4;j++) xvr[j]=xls[c*64+vv*4+j];
                for (int i=0;i<4;i++){
                    float w2=p2s[(ov*4+i)*65+c];
                    for (int j=0;j<4;j++) accV[i][j]+=w2*xvr[j];
                }
            }
            for (int i=0;i<4;i++)
                for (int j=0;j<4;j++)
                    Vs[(vv*4+j)*65 + ov*4+i]=accV[i][j]+b2s[ov*4+i];
        }
        __syncthreads();
        for (int v=0;v<64;v++){
            float mv[4], vv2[4];
            for (int j=0;j<4;j++) mv[j]=Ms[(wg*4+j)*65+v];
            for (int i=0;i<4;i++) vv2[i]=Vs[v*65+cg*4+i];
            for (int j=0;j<4;j++)
                for (int i=0;i<4;i++) acc[j][i]+=mv[j]*vv2[i];
        }
    }
    const float* xb = xadd + (size_t)b*CHW + (size_t)l*WW + w0;
    float*      ob = outp + (size_t)b*CHW + (size_t)l*WW + w0;
    for (int i=0;i<4;i++){
        int c=cg*4+i;
        for (int j=0;j<4;j++){
            int w=wg*4+j;
            float xv=xb[(size_t)c*HW+w];
            ob[(size_t)c*HW+w]=xv+coefs[c]*acc[j][i];
        }
    }
}

// ---------------- K6: cycle loss GEMMs via MFMA ----------------
// grid (6 wt, HH, 2 which), block 256 (4 waves; each wave 32x32 of the 64x64 out tile)
// which==0: D = P @ L        (A-op rows = P,  B-op rows = LT)
// which==1: D = L @ P        (A-op rows = L via LT-transposed staging, B-op rows = PT)
__global__ __launch_bounds__(256) void k6_mfma(
    const bf16* __restrict__ Pm, const bf16* __restrict__ LTm, const bf16* __restrict__ PTm,
    const float* __restrict__ mask_r2l, const float* __restrict__ mask_l2r,
    double* __restrict__ dsum, int b)
{
    __shared__ bf16 As[64*392];   // A-op slab [w][v=0..383], stride 392 (16B-aligned, bank-friendly)
    __shared__ bf16 Bs[64*72];    // B-op tile [u][v-tile]
    int t=threadIdx.x;
    int wt=blockIdx.x, l=blockIdx.y, which=blockIdx.z;
    int w0=wt*64, bh=b*HH+l;
    const float* msk = which ? (mask_r2l+(size_t)bh*WW) : (mask_l2r+(size_t)bh*WW);

    if (which==0){
        const bf16* src = Pm + (size_t)l*WW*WW + (size_t)w0*WW;
        for (int i=0;i<12;i++){
            int lin = t + 256*i;            // 0..3071 over 64 rows x 48 chunks
            int w = lin/48, c8 = lin - w*48;
            *reinterpret_cast<uint4*>(&As[w*392 + c8*8]) =
                *reinterpret_cast<const uint4*>(&src[(size_t)w*WW + c8*8]);
        }
    } else {
        // As[w][v] = L[w0+w][v] = LT[v][w0+w]
        const bf16* src = LTm + (size_t)l*WW*WW + w0;
        int wl = t&63, vb = t>>6;
        for (int i=0;i<96;i++){
            int v = vb + 4*i;
            As[wl*392 + v] = src[(size_t)v*WW + wl];
        }
    }

    const bf16* Bsrc = (which==0 ? LTm : PTm) + (size_t)l*WW*WW;
    int lane = t&63, wv = t>>6;
    int row32 = (wv>>1)*32, col32 = (wv&1)*32;
    int cn = lane&15, cq = lane>>4;

    float local = 0.f;
    for (int ut=0; ut<6; ut++){
        int u0 = ut*64;
        f4vec acc00={0,0,0,0}, acc01={0,0,0,0}, acc10={0,0,0,0}, acc11={0,0,0,0};
        for (int kt=0; kt<6; kt++){
            __syncthreads();
            for (int i=0;i<2;i++){
                int lin = t + 256*i;        // 0..511 over 64 rows x 8 chunks
                int u = lin>>3, c8 = lin&7;
                *reinterpret_cast<uint4*>(&Bs[u*72 + c8*8]) =
                    *reinterpret_cast<const uint4*>(&Bsrc[(size_t)(u0+u)*WW + kt*64 + c8*8]);
            }
            __syncthreads();
            for (int kk=0; kk<2; kk++){
                int ka = kt*64 + kk*32 + cq*8;
                int kb = kk*32 + cq*8;
                s8vec a0 = *reinterpret_cast<const s8vec*>(&As[(row32+cn)*392 + ka]);
                s8vec a1 = *reinterpret_cast<const s8vec*>(&As[(row32+16+cn)*392 + ka]);
                s8vec b0 = *reinterpret_cast<const s8vec*>(&Bs[(col32+cn)*72 + kb]);
                s8vec b1 = *reinterpret_cast<const s8vec*>(&Bs[(col32+16+cn)*72 + kb]);
                acc00 = __builtin_amdgcn_mfma_f32_16x16x32_bf16(a0,b0,acc00,0,0,0);
                acc01 = __builtin_amdgcn_mfma_f32_16x16x32_bf16(a0,b1,acc01,0,0,0);
                acc10 = __builtin_amdgcn_mfma_f32_16x16x32_bf16(a1,b0,acc10,0,0,0);
                acc11 = __builtin_amdgcn_mfma_f32_16x16x32_bf16(a1,b1,acc11,0,0,0);
            }
        }
        // C/D layout: col = lane&15, row = (lane>>4)*4 + reg
        int ua = u0 + col32 + cn;
        float m0v = msk[ua], m1v = msk[ua+16];
        int wbase = w0 + row32 + cq*4;
        for (int r=0;r<4;r++){
            int wa = wbase + r, wb_ = wbase + 16 + r;
            local += m0v * fabsf(acc00[r] - ((ua==wa)?1.f:0.f));
            local += m1v * fabsf(acc01[r] - ((ua+16==wa)?1.f:0.f));
            local += m0v * fabsf(acc10[r] - ((ua==wb_)?1.f:0.f));
            local += m1v * fabsf(acc11[r] - ((ua+16==wb_)?1.f:0.f));
        }
    }
    for (int o=32;o;o>>=1) local += __shfl_xor(local,o,64);
    if (lane==0) atomicAdd(&dsum[0], (double)local);
}

// ---------------- K7: photometric loss + LR passthrough ----------------
// grid (HH, 6), block 384
__global__ __launch_bounds__(384) void k7_photo(
    const bf16* __restrict__ Pm, const bf16* __restrict__ LTm,
    const float* __restrict__ mask_r2l, const float* __restrict__ mask_l2r,
    const float* __restrict__ LRl, const float* __restrict__ LRr,
    float* __restrict__ out2, float* __restrict__ out3, double* __restrict__ dsum, int b)
{
    __shared__ float lrl[3*WW], lrr[3*WW];
    int t=threadIdx.x, l=blockIdx.x, seg=blockIdx.y;
    int bh=b*HH+l;
    for (int c=0;c<3;c++){
        size_t idx=((size_t)(b*3+c)*HH+l)*WW+t;
        float vl=LRl[idx], vr=LRr[idx];
        lrl[c*WW+t]=vl; lrr[c*WW+t]=vr;
        if (seg==0){ out2[idx]=vl; out3[idx]=vr; }
    }
    __syncthreads();
    const bf16* Pb  = Pm  + (size_t)l*WW*WW;
    const bf16* LTb = LTm + (size_t)l*WW*WW;
    int lane=t&63, wid=t>>6;
    float local=0.f;
    for (int w=seg*64+wid; w<seg*64+64; w+=6){
        const bf16* prow = Pb  + (size_t)w*WW;
        const bf16* lrow = LTb + (size_t)w*WW;
        float a0=0.f,a1=0.f,a2=0.f, d0=0.f,d1=0.f,d2=0.f;
        for (int k=0;k<6;k++){
            int v=lane+64*k;
            float mp=b2f(prow[v]), ml=b2f(lrow[v]);
            a0+=mp*lrr[v]; a1+=mp*lrr[WW+v]; a2+=mp*lrr[2*WW+v];
            d0+=ml*lrl[v]; d1+=ml*lrl[WW+v]; d2+=ml*lrl[2*WW+v];
        }
        for (int o=32;o;o>>=1){
            a0+=__shfl_xor(a0,o,64); a1+=__shfl_xor(a1,o,64); a2+=__shfl_xor(a2,o,64);
            d0+=__shfl_xor(d0,o,64); d1+=__shfl_xor(d1,o,64); d2+=__shfl_xor(d2,o,64);
        }
        if (lane==0){
            float mkL=mask_l2r[bh*WW+w], mkR=mask_r2l[bh*WW+w];
            local += mkL*(fabsf(lrl[w]-a0)+fabsf(lrl[WW+w]-a1)+fabsf(lrl[2*WW+w]-a2));
            local += mkR*(fabsf(lrr[w]-d0)+fabsf(lrr[WW+w]-d1)+fabsf(lrr[2*WW+w]-d2));
        }
    }
    if (lane==0) atomicAdd(&dsum[1],(double)local);
}

// ---------------- K8: smoothness losses (pure row scans of P, LT) ----------------
// grid (HH, 6), block 384
__global__ __launch_bounds__(384) void k8_smooth(
    const bf16* __restrict__ Pm, const bf16* __restrict__ LTm,
    double* __restrict__ dsum, int b)
{
    (void)b;
    int t=threadIdx.x, l=blockIdx.x, seg=blockIdx.y;
    const bf16* Pb  = Pm  + (size_t)l*WW*WW;
    const bf16* LTb = LTm + (size_t)l*WW*WW;
    int lane=t&63, wid=t>>6;
    bool hasnext = (l < HH-1);
    float lw=0.f, lh=0.f;
    for (int w=seg*64+wid; w<seg*64+64; w+=6){
        const bf16* p0  = Pb  + (size_t)w*WW;
        const bf16* lt0 = LTb + (size_t)w*WW;
        if (w < WW-1){
            const bf16* p1  = p0 + WW;
            const bf16* lt1 = lt0 + WW;
            for (int k=0;k<6;k++){
                int v=lane+64*k;
                if (v < WW-1){
                    lw += fabsf(b2f(p0[v]) - b2f(p1[v+1]));
                    lw += fabsf(b2f(lt0[v]) - b2f(lt1[v+1]));
                }
            }
        }
        if (hasnext){
            const bf16* pn  = p0  + (size_t)WW*WW;
            const bf16* ltn = lt0 + (size_t)WW*WW;
            for (int k=0;k<6;k++){
                int v=lane+64*k;
                lh += fabsf(b2f(p0[v]) - b2f(pn[v]));
                lh += fabsf(b2f(lt0[v]) - b2f(ltn[v]));
            }
        }
    }
    for (int o=32;o;o>>=1){ lw+=__shfl_xor(lw,o,64); lh+=__shfl_xor(lh,o,64); }
    if (lane==0){
        atomicAdd(&dsum[3],(double)lw);
        atomicAdd(&dsum[2],(double)lh);
    }
}

// ---------------- K9: final loss ----------------
__global__ void k9_final(const double* __restrict__ dsum, const float* __restrict__ lossin,
                         float* __restrict__ out4)
{
    if (threadIdx.x==0){
        double cyc  = dsum[0]/(double)((size_t)BB*HH*WW*WW);
        double photo= dsum[1]/(double)((size_t)BB*3*HH*WW);
        double lhv  = dsum[2]/(double)((size_t)BB*(HH-1)*WW*WW);
        double lwv  = dsum[3]/(double)((size_t)BB*HH*(WW-1)*(WW-1));
        double res  = (double)lossin[0] + 0.0025*(photo + 0.1*(lwv+lhv) + cyc);
        out4[0]=(float)res;
    }
}

extern "C" void kernel_launch(void* const* d_in, const int* in_sizes, int n_in,
                              void* d_out, int out_size, void* d_ws, size_t ws_size,
                              hipStream_t stream)
{
    (void)in_sizes; (void)n_in; (void)out_size; (void)ws_size;
    const float* x_l  = (const float*)d_in[0];
    const float* x_r  = (const float*)d_in[1];
    const float* LRl  = (const float*)d_in[2];
    const float* LRr  = (const float*)d_in[3];
    const float* lossi= (const float*)d_in[4];
    const float* nlw  = (const float*)d_in[5];
    const float* nlb  = (const float*)d_in[6];
    const float* nrw  = (const float*)d_in[7];
    const float* nrb  = (const float*)d_in[8];
    const float* lp1w = (const float*)d_in[9];
    const float* lp1b = (const float*)d_in[10];
    const float* rp1w = (const float*)d_in[11];
    const float* rp1b = (const float*)d_in[12];
    const float* lp2w = (const float*)d_in[13];
    const float* lp2b = (const float*)d_in[14];
    const float* rp2w = (const float*)d_in[15];
    const float* rp2b = (const float*)d_in[16];
    const float* beta = (const float*)d_in[17];
    const float* gamma= (const float*)d_in[18];

    bf16* Abuf = (bf16*)d_ws;             // A -> P in-place
    bf16* LTb  = Abuf + ACHUNK;
    bf16* PTb  = Abuf + 2*ACHUNK;
    float* wsf = (float*)((char*)d_ws + 3*ACHUNK*2);
    float* rmax=wsf, *irsum=wsf+SST, *cmax=wsf+2*SST, *icsum=wsf+3*SST;
    float* mask_r2l=wsf+4*SST, *mask_l2r=wsf+5*SST;
    double* dsum=(double*)(wsf+6*SST);

    float* out  = (float*)d_out;
    float* out0 = out;
    float* out1 = out + (size_t)BB*CHW;
    float* out2 = out + 2*(size_t)BB*CHW;
    float* out3 = out2 + (size_t)BB*3*HW;
    float* out4 = out3 + (size_t)BB*3*HW;

    k0_zero<<<1,64,0,stream>>>(dsum);
    for (int b=0;b<BB;b++){
        k2f<<<dim3(6,HH),256,0,stream>>>(x_l,x_r,nlw,nlb,nrw,nrb,lp1w,lp1b,rp1w,rp1b,Abuf,b);
        k3_stats<<<dim3(HH,6),384,0,stream>>>(Abuf,rmax,irsum,cmax,icsum,b);
        k_mats<<<dim3(HH,6),256,0,stream>>>(Abuf,LTb,rmax,irsum,cmax,icsum,b);
        k_trans<<<dim3(6,6,HH),256,0,stream>>>(Abuf,PTb);
        k4_masks<<<dim3(HH,6),384,0,stream>>>(Abuf,LTb,mask_r2l,mask_l2r,b);
        k5f<<<dim3(6,HH),256,0,stream>>>(Abuf,x_r,rp2w,rp2b,x_l,beta, out0,b,0);
        k5f<<<dim3(6,HH),256,0,stream>>>(LTb, x_l,lp2w,lp2b,x_r,gamma,out1,b,1);
        k6_mfma<<<dim3(6,HH,2),256,0,stream>>>(Abuf,LTb,PTb,mask_r2l,mask_l2r,dsum,b);
        k7_photo<<<dim3(HH,6),384,0,stream>>>(Abuf,LTb,mask_r2l,mask_l2r,LRl,LRr,out2,out3,dsum,b);
        k8_smooth<<<dim3(HH,6),384,0,stream>>>(Abuf,LTb,dsum,b);
    }
    k9_final<<<1,64,0,stream>>>(dsum,lossi,out4);
}